// Round 16
// baseline (662.155 us; speedup 1.0000x reference)
//
#include <hip/hip_runtime.h>
#include <math.h>

typedef unsigned long long u64;
typedef unsigned short u16;
typedef __attribute__((ext_vector_type(8))) short bf16x8;
typedef __attribute__((ext_vector_type(4))) float f32x4;

#define N_ANCH 2304
#define NP     2000
#define W1     36   // 2304/64
#define W2     32   // ceil(2000/64)

// ---------- output offsets (floats) ----------
#define O_RPN_LOGITS   0
#define O_RPN_DELTAS   4608
#define O_PROPOSALS    13824
#define O_ANCHORS      21824
#define O_RCNN_LOGITS  31040
#define O_RCNN_DELTAS  35040
#define O_RCNN_MASKS   43040
#define O_FINAL_DETS   435040
#define O_FINAL_MASKS  443040
#define O_FINAL_SCORES 835040
#define O_KEEP2        837040

__device__ __forceinline__ u16 f2bf(float f) {
    unsigned int x = __float_as_uint(f);
    unsigned int r = x + 0x7fffu + ((x >> 16) & 1u);   // RTNE
    return (u16)(r >> 16);
}

// ============================================================
// K1: backbone conv + relu -> feat [64,16,16] and feat_tf [pix][64]
// ============================================================
__global__ __launch_bounds__(256) void bb_conv(const float* __restrict__ x,
    const float* __restrict__ w, const float* __restrict__ b,
    float* __restrict__ feat, float* __restrict__ feat_tf)
{
    __shared__ float ws_[768];
    int c = blockIdx.x;
    for (int e = threadIdx.x; e < 768; e += 256) ws_[e] = w[c*768 + e];
    __syncthreads();
    int fy = threadIdx.x >> 4, fx = threadIdx.x & 15;
    float acc = b[c];
    for (int ic = 0; ic < 3; ++ic)
        for (int ky = 0; ky < 16; ++ky) {
            const float* xr = x + (size_t)(ic*256 + fy*16+ky)*256 + fx*16;
            const float* wr = ws_ + ic*256 + ky*16;
            #pragma unroll
            for (int kx = 0; kx < 16; ++kx) acc += xr[kx]*wr[kx];
        }
    float v = fmaxf(acc, 0.f);
    feat[c*256 + threadIdx.x] = v;
    feat_tf[threadIdx.x*64 + c] = v;
}

// ============================================================
// K2: RPN 3x3 SAME conv + relu -> h [64,16,16]
// ============================================================
__global__ __launch_bounds__(256) void rpn_conv(const float* __restrict__ feat,
    const float* __restrict__ w, const float* __restrict__ b, float* __restrict__ h)
{
    __shared__ float f[16384];
    __shared__ float ws_[576];
    int c = blockIdx.x;
    for (int e = threadIdx.x; e < 16384; e += 256) f[e] = feat[e];
    for (int e = threadIdx.x; e < 576; e += 256) ws_[e] = w[c*576 + e];
    __syncthreads();
    int fy = threadIdx.x >> 4, fx = threadIdx.x & 15;
    float acc = b[c];
    for (int ic = 0; ic < 64; ++ic) {
        const float* fc = f + ic*256;
        const float* wc = ws_ + ic*9;
        #pragma unroll
        for (int dy = 0; dy < 3; ++dy) {
            int y = fy + dy - 1;
            if (y < 0 || y > 15) continue;
            #pragma unroll
            for (int dx = 0; dx < 3; ++dx) {
                int xx = fx + dx - 1;
                if (xx < 0 || xx > 15) continue;
                acc += fc[y*16+xx]*wc[dy*3+dx];
            }
        }
    }
    h[c*256 + threadIdx.x] = fmaxf(acc, 0.f);
}

// ============================================================
// K3: RPN heads (1x1 convs) + softmax + anchors + decode + clip
// ============================================================
__global__ __launch_bounds__(256) void heads_rpn(const float* __restrict__ hbuf,
    const float* __restrict__ w_cls, const float* __restrict__ b_cls,
    const float* __restrict__ w_box, const float* __restrict__ b_box,
    float* __restrict__ out_logits, float* __restrict__ out_deltas,
    float* __restrict__ out_anchors,
    float* __restrict__ scores, float* __restrict__ boxes)
{
    int idx = blockIdx.x*256 + threadIdx.x;
    if (idx >= N_ANCH) return;
    int fy = idx / 144, r = idx % 144, fx = r / 9, a = r % 9;
    int pix = fy*16 + fx;
    float l0 = b_cls[a*2+0], l1 = b_cls[a*2+1];
    float d0 = b_box[a*4+0], d1 = b_box[a*4+1], d2 = b_box[a*4+2], d3 = b_box[a*4+3];
    const float* wc0 = w_cls + (a*2+0)*64;
    const float* wc1 = w_cls + (a*2+1)*64;
    const float* wb0 = w_box + (a*4+0)*64;
    const float* wb1 = w_box + (a*4+1)*64;
    const float* wb2 = w_box + (a*4+2)*64;
    const float* wb3 = w_box + (a*4+3)*64;
    for (int c = 0; c < 64; ++c) {
        float hv = hbuf[c*256 + pix];
        l0 += hv*wc0[c]; l1 += hv*wc1[c];
        d0 += hv*wb0[c]; d1 += hv*wb1[c]; d2 += hv*wb2[c]; d3 += hv*wb3[c];
    }
    out_logits[idx*2+0] = l0; out_logits[idx*2+1] = l1;
    out_deltas[idx*4+0] = d0; out_deltas[idx*4+1] = d1;
    out_deltas[idx*4+2] = d2; out_deltas[idx*4+3] = d3;
    float mx = fmaxf(l0,l1);
    float e0 = expf(l0-mx), e1 = expf(l1-mx);
    scores[idx] = e1/(e0+e1);
    float SC = (a/3 == 0) ? 32.f : ((a/3 == 1) ? 64.f : 128.f);
    float RT = (a%3 == 0) ? 0.5f : ((a%3 == 1) ? 1.f : 2.f);
    float wsz = SC*sqrtf(RT), hsz = SC/sqrtf(RT);
    float cx = (fx+0.5f)*16.f, cy = (fy+0.5f)*16.f;
    float ax1 = cx - wsz*0.5f, ay1 = cy - hsz*0.5f;
    float ax2 = cx + wsz*0.5f, ay2 = cy + hsz*0.5f;
    out_anchors[idx*4+0]=ax1; out_anchors[idx*4+1]=ay1;
    out_anchors[idx*4+2]=ax2; out_anchors[idx*4+3]=ay2;
    float aw = ax2-ax1, ah = ay2-ay1;
    float acx = ax1 + 0.5f*aw, acy = ay1 + 0.5f*ah;
    float ncx = acx + d0*aw, ncy = acy + d1*ah;
    float nw = aw*expf(d2), nh = ah*expf(d3);
    float x1 = ncx - 0.5f*nw, y1 = ncy - 0.5f*nh;
    float x2 = ncx + 0.5f*nw, y2 = ncy + 0.5f*nh;
    const float lim = 255.f;
    x1 = fminf(fmaxf(x1,0.f),lim); y1 = fminf(fmaxf(y1,0.f),lim);
    x2 = fminf(fmaxf(x2,0.f),lim); y2 = fminf(fmaxf(y2,0.f),lim);
    boxes[idx*4+0]=x1; boxes[idx*4+1]=y1; boxes[idx*4+2]=x2; boxes[idx*4+3]=y2;
}

// ============================================================
// stable descending argsort by rank counting (matches jnp.argsort(-s))
// ============================================================
__global__ __launch_bounds__(256) void sort_rank(const float* __restrict__ score,
                                                 int* __restrict__ order, int n)
{
    __shared__ float sc[2304];
    for (int i = threadIdx.x; i < n; i += 256) sc[i] = score[i];
    __syncthreads();
    int i = blockIdx.x*256 + threadIdx.x;
    if (i >= n) return;
    float si = sc[i];
    int r = 0;
    for (int j = 0; j < n; ++j) {
        float sj = sc[j];
        r += (sj > si) || (sj == si && j < i);
    }
    order[r] = i;
}

__global__ __launch_bounds__(256) void gather_sorted(const float4* __restrict__ boxes,
    const int* __restrict__ order, float4* __restrict__ sb, float* __restrict__ sa, int n)
{
    int i = blockIdx.x*256 + threadIdx.x;
    if (i >= n) return;
    float4 b = boxes[order[i]];
    sb[i] = b;
    sa[i] = fmaxf(b.z-b.x, 0.f)*fmaxf(b.w-b.y, 0.f);
}

// ============================================================
// IoU suppression bitmask (bits only for j > i); rows [n, ntotal) zeroed
// ============================================================
__global__ __launch_bounds__(256) void iou_mask(const float4* __restrict__ sb,
    const float* __restrict__ sa, int n, int ntotal, int words, float thr,
    u64* __restrict__ mask)
{
    int gid = blockIdx.x*256 + threadIdx.x;
    if (gid >= ntotal*words) return;
    int i = gid / words, w = gid % words;
    if (i >= n) { mask[(size_t)i*words + w] = 0; return; }
    float4 bi = sb[i]; float ai = sa[i];
    u64 m = 0;
    int j0 = w*64;
    for (int bb = 0; bb < 64; ++bb) {
        int j = j0 + bb;
        if (j > i && j < n) {
            float4 bj = sb[j];
            float xx1 = fmaxf(bi.x, bj.x), yy1 = fmaxf(bi.y, bj.y);
            float xx2 = fminf(bi.z, bj.z), yy2 = fminf(bi.w, bj.w);
            float inter = fmaxf(xx2-xx1, 0.f)*fmaxf(yy2-yy1, 0.f);
            float iou = inter / (ai + sa[j] - inter + 1e-8f);
            if (iou > thr) m |= 1ULL << bb;
        }
    }
    mask[(size_t)i*words + w] = m;
}

// ============================================================
// workgroup-parallel blocked greedy NMS scan (256 threads).
// ALL global loads unconditional (clamped; dupes idempotent under AND).
// mask must have (nblk+1)*64 rows allocated (last 64 = slack).
// ============================================================
__global__ __launch_bounds__(256, 1) void nms_scan_wg(const u64* __restrict__ mask,
    int nblk, int words, u64* __restrict__ remout)
{
    __shared__ u64 rem_lds[64];
    __shared__ u64 diagS[64];
    __shared__ u64 pslot[8*64];
    int t = threadIdx.x;
    int ngrp = 256 / words;              // 36->7, 32->8
    int g = t / words, c = t % words;
    bool pactive = (g < ngrp);
    int gg = min(g, ngrp - 1);
    if (t < 64) {
        rem_lds[t] = ~0ULL;
        diagS[t] = mask[(size_t)t*words + 0];
    }
    __syncthreads();
    for (int b = 0; b < nblk; ++b) {
        const u64* blockbase = mask + (size_t)(64*b)*words;
        u64 vals[10];
        int rows[10];
        #pragma unroll
        for (int k = 0; k < 10; ++k) {
            int r = min(gg + k*ngrp, 63);
            rows[k] = r;
            vals[k] = blockbase[(size_t)r*words + c];
        }
        u64 dnext = mask[(size_t)(64*(b+1) + (t & 63))*words + min(b+1, words-1)];
        // sparse serial resolve (readlane on chain)
        u64 mydia = diagS[t & 63];
        u64 nz = __ballot(mydia != 0ULL);
        u64 cur = rem_lds[b];
        u64 pend = cur & nz;
        unsigned mlo = (unsigned)mydia;
        unsigned mhi = (unsigned)(mydia >> 32);
        while (pend) {
            int i = __ffsll((unsigned long long)pend) - 1;
            unsigned lo = __builtin_amdgcn_readlane((int)mlo, i);
            unsigned hi = __builtin_amdgcn_readlane((int)mhi, i);
            u64 dia = ((u64)hi << 32) | lo;
            cur  &= ~dia;
            pend &= ~dia;
            pend &= pend - 1;
        }
        u64 partial = ~0ULL;
        #pragma unroll
        for (int k = 0; k < 10; ++k) {
            bool al = (cur >> rows[k]) & 1ULL;
            partial &= al ? ~vals[k] : ~0ULL;
        }
        if (pactive) pslot[g*64 + c] = partial;
        __syncthreads();
        if (t < 64) diagS[t] = dnext;
        if (t < words) {
            u64 red = rem_lds[t];
            for (int g2 = 0; g2 < ngrp; ++g2) red &= pslot[g2*64 + t];
            rem_lds[t] = red;
        }
        __syncthreads();
    }
    if (t < words) remout[t] = rem_lds[t];
}

// ============================================================
// kept-first stable selection -> proposals / valid
// ============================================================
__global__ __launch_bounds__(256) void select_props(const u64* __restrict__ remw,
    const float4* __restrict__ sboxes, float* __restrict__ prop_out,
    float4* __restrict__ propws, int* __restrict__ validat)
{
    __shared__ int cnt[256];
    __shared__ int pref[257];
    int t = threadIdx.x;
    int base = t*9;
    int c = 0;
    #pragma unroll
    for (int q = 0; q < 9; ++q) { int i = base+q; c += (int)((remw[i>>6]>>(i&63))&1ULL); }
    cnt[t] = c; __syncthreads();
    if (t == 0) { pref[0]=0; for (int u=0;u<256;u++) pref[u+1]=pref[u]+cnt[u]; }
    __syncthreads();
    int K = pref[256];
    int kb = pref[t];
    int nb = K + (base - pref[t]);
    for (int q = 0; q < 9; ++q) {
        int i = base + q;
        int k = (int)((remw[i>>6]>>(i&63))&1ULL);
        int pos = k ? kb : nb;
        if (k) kb++; else nb++;
        if (pos < NP) {
            validat[pos] = k;
            float4 p = k ? sboxes[i] : make_float4(0.f,0.f,0.f,0.f);
            propws[pos] = p;
            prop_out[pos*4+0]=p.x; prop_out[pos*4+1]=p.y;
            prop_out[pos*4+2]=p.z; prop_out[pos*4+3]=p.w;
        }
    }
}

// ============================================================
// weight prep for MFMA mask conv: wbt[tap][oc][ic] (bf16)
// ============================================================
__global__ __launch_bounds__(256) void prep_wbt(const float* __restrict__ w, u16* __restrict__ wbt)
{
    int e = blockIdx.x*256 + threadIdx.x;
    if (e >= 36864) return;
    int oc = e / 576, rem = e % 576, ic = rem / 9, tap = rem % 9;
    wbt[tap*4096 + oc*64 + ic] = f2bf(w[e]);
}

// ============================================================
// K10: FUSED crop + 2x2 maxpool (-> flat, bit-exact f32) + MFMA mask head.
// A-reuse restructure: wave w owns pixel tiles {w, w+4, w+8, w+12} and ALL
// 64 oc (4 oc-tiles). Per (tap, pt) the A-fragment is read from LDS ONCE
// and used by 8 MFMAs (4 ocT x 2 K-halves) -> LDS b128 reads per block
// drop ~4x vs one-ocT-per-wave. Weight B-frags come from global (L2-hot).
// Epilogue: each pixel owned by one wave -> per-lane ocT sum + 16-lane
// shfl reduce, staged in LDS, coalesced store.
// pooled[] via u32 atomicMax (bit-exact non-neg f32 max).
// ============================================================
__global__ __launch_bounds__(256) void mask_head_fused(const float* __restrict__ feat_tf,
    const float4* __restrict__ propws, const u16* __restrict__ wbt,
    const float* __restrict__ b_m1, const float* __restrict__ w_m2,
    const float* __restrict__ b_m2, float* __restrict__ masks_out,
    float* __restrict__ flat)
{
    __shared__ __align__(16) u16 crop[256*72];
    __shared__ unsigned pooled[3136];
    __shared__ float part[208];
    int n = blockIdx.x;
    int t = threadIdx.x;
    float4 p = propws[n];
    float x1n = p.x*(1.f/255.f), y1n = p.y*(1.f/255.f);
    float x2n = p.z*(1.f/255.f), y2n = p.w*(1.f/255.f);
    for (int e = t; e < 3136; e += 256) pooled[e] = 0;
    __syncthreads();
    int wave = t >> 6, lane = t & 63;
    for (int it = 0; it < 64; ++it) {
        int g = it*4 + wave;                 // wave-uniform
        int py = (g >> 4) - 1, px = (g & 15) - 1;
        u16 ov = 0;
        if ((unsigned)py < 14u && (unsigned)px < 14u) {   // uniform branch
            float fyv = (y1n + (y2n-y1n)*(py*(1.f/13.f)))*15.f;
            float fxv = (x1n + (x2n-x1n)*(px*(1.f/13.f)))*15.f;
            int y0 = min(max((int)floorf(fyv),0),15), y1i = min(y0+1,15);
            int x0 = min(max((int)floorf(fxv),0),15), x1i = min(x0+1,15);
            float wy = fyv - (float)y0, wx = fxv - (float)x0;
            float v00 = feat_tf[(y0*16+x0)*64 + lane];
            float v01 = feat_tf[(y0*16+x1i)*64 + lane];
            float v10 = feat_tf[(y1i*16+x0)*64 + lane];
            float v11 = feat_tf[(y1i*16+x1i)*64 + lane];
            float top = v00*(1.f-wx) + v01*wx;
            float bot = v10*(1.f-wx) + v11*wx;
            float val = top*(1.f-wy) + bot*wy;
            ov = f2bf(val);
            int q = (py >> 1)*7 + (px >> 1);
            atomicMax(&pooled[lane*49 + q], __float_as_uint(val));
        }
        crop[g*72 + lane] = ov;
    }
    __syncthreads();
    // emit flat (bit-exact pooled max)
    {
        size_t rowoff = (size_t)n*3136;
        for (int k = t; k < 3136; k += 256)
            flat[rowoff + k] = __uint_as_float(pooled[k]);
    }

    int quad = lane >> 4, l15 = lane & 15;
    // accumulators: acc[ip][ocT], pixel tile pt = wave + ip*4
    f32x4 acc[4][4];
    #pragma unroll
    for (int ocT = 0; ocT < 4; ++ocT) {
        float bv = b_m1[ocT*16 + l15];
        #pragma unroll
        for (int ip = 0; ip < 4; ++ip)
            acc[ip][ocT] = (f32x4){bv, bv, bv, bv};
    }
    int prow[4];
    #pragma unroll
    for (int ip = 0; ip < 4; ++ip) {
        int pt = wave + ip*4;
        int pix = min(pt, 12)*16 + l15;
        int py = pix / 14, px = pix - py*14;
        prow[ip] = (pt < 13 && pix < 196) ? ((py+1)*16 + px + 1) : 17;
    }

    for (int tap = 0; tap < 9; ++tap) {
        int doff = (tap/3 - 1)*16 + (tap%3 - 1);
        const u16* wt = wbt + tap*4096;
        bf16x8 bw[4][2];
        #pragma unroll
        for (int ocT = 0; ocT < 4; ++ocT) {
            bw[ocT][0] = *(const bf16x8*)(wt + (ocT*16+l15)*64 +      quad*8);
            bw[ocT][1] = *(const bf16x8*)(wt + (ocT*16+l15)*64 + 32 + quad*8);
        }
        #pragma unroll
        for (int ip = 0; ip < 4; ++ip) {
            int base = (prow[ip] + doff)*72 + quad*8;
            bf16x8 a0 = *(const bf16x8*)(crop + base);
            bf16x8 a1 = *(const bf16x8*)(crop + base + 32);
            #pragma unroll
            for (int ocT = 0; ocT < 4; ++ocT) {
                acc[ip][ocT] = __builtin_amdgcn_mfma_f32_16x16x32_bf16(a0, bw[ocT][0], acc[ip][ocT], 0, 0, 0);
                acc[ip][ocT] = __builtin_amdgcn_mfma_f32_16x16x32_bf16(a1, bw[ocT][1], acc[ip][ocT], 0, 0, 0);
            }
        }
    }

    // epilogue: per-pixel oc-sum, one wave owns each pixel
    float wm2[4];
    #pragma unroll
    for (int ocT = 0; ocT < 4; ++ocT) wm2[ocT] = w_m2[ocT*16 + l15];
    #pragma unroll
    for (int ip = 0; ip < 4; ++ip) {
        int pt = wave + ip*4;
        #pragma unroll
        for (int r = 0; r < 4; ++r) {
            float s = 0.f;
            #pragma unroll
            for (int ocT = 0; ocT < 4; ++ocT)
                s += fmaxf(acc[ip][ocT][r], 0.f) * wm2[ocT];
            s += __shfl_xor(s, 1);
            s += __shfl_xor(s, 2);
            s += __shfl_xor(s, 4);
            s += __shfl_xor(s, 8);
            int pix = pt*16 + quad*4 + r;
            if (l15 == 0 && pt < 13 && pix < 196) part[pix] = s;
        }
    }
    __syncthreads();
    for (int tt = t; tt < 196; tt += 256)
        masks_out[(size_t)n*196 + tt] = part[tt] + b_m2[0];
}

// ============================================================
// f32 GEMM partial over K-split (exact fmaf chain per k-range).
// ============================================================
__global__ __launch_bounds__(256) void gemm_f32_part(const float* __restrict__ A,
    const float* __restrict__ B, float* __restrict__ Cpart,
    int M, int N, int K, int Kblk)
{
    __shared__ float As[32][68];
    __shared__ float Bs[32][68];
    int row0 = blockIdx.x*64, col0 = blockIdx.y*64;
    int s = blockIdx.z;
    int kbase = s*Kblk;
    int t = threadIdx.x;
    int tx = t & 15, ty = t >> 4;
    int ar = t >> 2;
    int ak = (t & 3) * 8;
    int am = min(row0 + ar, M-1);
    const float* Arow = A + (size_t)am*K + kbase;
    int bk = t >> 3;
    int bc = (t & 7) * 8;
    const float* Bbase = B + (size_t)(kbase + bk)*N + col0 + bc;

    float4 pa0 = *(const float4*)(Arow + ak);
    float4 pa1 = *(const float4*)(Arow + ak + 4);
    float4 pb0 = *(const float4*)(Bbase);
    float4 pb1 = *(const float4*)(Bbase + 4);

    float acc[4][4] = {};
    for (int k0 = 0; k0 < Kblk; k0 += 32) {
        As[ak+0][ar]=pa0.x; As[ak+1][ar]=pa0.y; As[ak+2][ar]=pa0.z; As[ak+3][ar]=pa0.w;
        As[ak+4][ar]=pa1.x; As[ak+5][ar]=pa1.y; As[ak+6][ar]=pa1.z; As[ak+7][ar]=pa1.w;
        *(float4*)&Bs[bk][bc]   = pb0;
        *(float4*)&Bs[bk][bc+4] = pb1;
        __syncthreads();
        int kn = k0 + 32;
        if (kn < Kblk) {
            pa0 = *(const float4*)(Arow + kn + ak);
            pa1 = *(const float4*)(Arow + kn + ak + 4);
            pb0 = *(const float4*)(Bbase + (size_t)kn*N);
            pb1 = *(const float4*)(Bbase + (size_t)kn*N + 4);
        }
        #pragma unroll
        for (int k = 0; k < 32; ++k) {
            float4 av = *(float4*)&As[k][ty*4];
            float4 bv = *(float4*)&Bs[k][tx*4];
            float a_[4] = {av.x, av.y, av.z, av.w};
            float b_[4] = {bv.x, bv.y, bv.z, bv.w};
            #pragma unroll
            for (int i = 0; i < 4; ++i)
                #pragma unroll
                for (int j = 0; j < 4; ++j)
                    acc[i][j] = fmaf(a_[i], b_[j], acc[i][j]);
        }
        __syncthreads();
    }
    float* Cp = Cpart + (size_t)s*M*N;
    #pragma unroll
    for (int i = 0; i < 4; ++i) {
        int gm = row0 + ty*4 + i;
        if (gm >= M) continue;
        #pragma unroll
        for (int j = 0; j < 4; ++j) {
            int gn = col0 + tx*4 + j;
            Cp[(size_t)gm*N + gn] = acc[i][j];
        }
    }
}

// ============================================================
// combine K-split partials in ascending-s order + bias + optional relu.
// ============================================================
__global__ __launch_bounds__(256) void combine_parts(const float* __restrict__ parts,
    const float* __restrict__ bias, float* __restrict__ C,
    int MN, int N, int S, int relu)
{
    int i4 = blockIdx.x*256 + threadIdx.x;
    if (i4*4 >= MN) return;
    size_t idx = (size_t)i4*4;
    float4 acc = *(const float4*)(parts + idx);
    for (int s = 1; s < S; ++s) {
        float4 v = *(const float4*)(parts + (size_t)s*MN + idx);
        acc.x += v.x; acc.y += v.y; acc.z += v.z; acc.w += v.w;
    }
    int nb = (int)(idx & (N-1));
    float4 bv = *(const float4*)(bias + nb);
    acc.x += bv.x; acc.y += bv.y; acc.z += bv.z; acc.w += bv.w;
    if (relu) {
        acc.x = fmaxf(acc.x, 0.f); acc.y = fmaxf(acc.y, 0.f);
        acc.z = fmaxf(acc.z, 0.f); acc.w = fmaxf(acc.w, 0.f);
    }
    *(float4*)(C + idx) = acc;
}

// ============================================================
// K9: rcnn heads — coalesced LDS staging, then 8 serial threads replay
// the sequential fmaf chain bit-exactly.
// ============================================================
__global__ __launch_bounds__(256) void rcnn_heads_lds(const float* __restrict__ h2,
    const float* __restrict__ w_rcls, const float* __restrict__ b_rcls,
    const float* __restrict__ w_rbox, const float* __restrict__ b_rbox,
    const float4* __restrict__ propws, const int* __restrict__ validat,
    float* __restrict__ out_logits, float* __restrict__ out_deltas,
    float4* __restrict__ dets, float* __restrict__ dscores, float* __restrict__ s2)
{
    __shared__ float hs[8*520];
    int b0 = blockIdx.x*8;
    for (int e = threadIdx.x; e < 8*512; e += 256) {
        int pr = e >> 9, k = e & 511;
        hs[pr*520 + k] = h2[(size_t)(b0+pr)*512 + k];
    }
    __syncthreads();
    int t = threadIdx.x;
    if (t >= 8) return;
    int n = b0 + t;
    const float* hv = hs + t*520;
    float l0 = b_rcls[0], l1 = b_rcls[1];
    float d0 = b_rbox[0], d1 = b_rbox[1], d2 = b_rbox[2], d3 = b_rbox[3];
    for (int k = 0; k < 512; ++k) {
        float v = hv[k];
        l0 = fmaf(v, w_rcls[k*2+0], l0); l1 = fmaf(v, w_rcls[k*2+1], l1);
        d0 = fmaf(v, w_rbox[k*4+0], d0); d1 = fmaf(v, w_rbox[k*4+1], d1);
        d2 = fmaf(v, w_rbox[k*4+2], d2); d3 = fmaf(v, w_rbox[k*4+3], d3);
    }
    out_logits[n*2+0]=l0; out_logits[n*2+1]=l1;
    out_deltas[n*4+0]=d0; out_deltas[n*4+1]=d1;
    out_deltas[n*4+2]=d2; out_deltas[n*4+3]=d3;
    float mx = fmaxf(l0,l1);
    float e0 = expf(l0-mx), e1 = expf(l1-mx);
    float sc = e1/(e0+e1);
    float4 p = propws[n];
    float w = p.z-p.x, h = p.w-p.y;
    float cx = p.x + 0.5f*w, cy = p.y + 0.5f*h;
    float ncx = cx + d0*w, ncy = cy + d1*h;
    float nw = w*expf(d2), nh = h*expf(d3);
    float x1 = ncx-0.5f*nw, y1 = ncy-0.5f*nh, x2 = ncx+0.5f*nw, y2 = ncy+0.5f*nh;
    const float lim = 255.f;
    x1 = fminf(fmaxf(x1,0.f),lim); y1 = fminf(fmaxf(y1,0.f),lim);
    x2 = fminf(fmaxf(x2,0.f),lim); y2 = fminf(fmaxf(y2,0.f),lim);
    dets[n] = make_float4(x1,y1,x2,y2);
    dscores[n] = sc;
    s2[n] = validat[n] ? sc : -1.0f;
}

// ============================================================
// final outputs
// ============================================================
__global__ void finalize(const u64* __restrict__ remw2,
    const int* __restrict__ order2, const int* __restrict__ validat,
    const float4* __restrict__ dets, const float* __restrict__ dscores,
    const float* __restrict__ masks_in, float* __restrict__ fdets,
    float* __restrict__ fscores, float* __restrict__ fmasks, float* __restrict__ keep2out)
{
    int j = blockIdx.x;
    int t = threadIdx.x;
    int o = order2[j];
    int kb = (int)((remw2[j>>6] >> (j&63)) & 1ULL);
    int k2 = kb & validat[o];
    if (t == 0) {
        float4 d = dets[o];
        if (!k2) d = make_float4(0.f,0.f,0.f,0.f);
        fdets[j*4+0]=d.x; fdets[j*4+1]=d.y; fdets[j*4+2]=d.z; fdets[j*4+3]=d.w;
        fscores[j] = k2 ? dscores[o] : 0.f;
        keep2out[j] = (float)k2;
    }
    if (t < 196) {
        float mv = masks_in[(size_t)o*196 + t];
        float sg = 1.f/(1.f + expf(-mv));
        fmasks[(size_t)j*196 + t] = k2 ? sg : 0.f;
    }
}

// ============================================================
extern "C" void kernel_launch(void* const* d_in, const int* in_sizes, int n_in,
                              void* d_out, int out_size, void* d_ws, size_t ws_size,
                              hipStream_t stream)
{
    const float* x      = (const float*)d_in[0];
    const float* w_bb   = (const float*)d_in[1];
    const float* b_bb   = (const float*)d_in[2];
    const float* w_rpn  = (const float*)d_in[3];
    const float* b_rpn  = (const float*)d_in[4];
    const float* w_cls  = (const float*)d_in[5];
    const float* b_cls  = (const float*)d_in[6];
    const float* w_box  = (const float*)d_in[7];
    const float* b_box  = (const float*)d_in[8];
    const float* w_fc1  = (const float*)d_in[9];
    const float* b_fc1  = (const float*)d_in[10];
    const float* w_fc2  = (const float*)d_in[11];
    const float* b_fc2  = (const float*)d_in[12];
    const float* w_rcls = (const float*)d_in[13];
    const float* b_rcls = (const float*)d_in[14];
    const float* w_rbox = (const float*)d_in[15];
    const float* b_rbox = (const float*)d_in[16];
    const float* w_m1   = (const float*)d_in[17];
    const float* b_m1   = (const float*)d_in[18];
    const float* w_m2   = (const float*)d_in[19];
    const float* b_m2   = (const float*)d_in[20];

    float* out = (float*)d_out;

    // ---- workspace carve-up (256B-aligned chunks) ----
    char* basep = (char*)d_ws;
    auto alloc = [&](size_t bytes) { char* q = basep; basep += (bytes + 255) & ~(size_t)255; return q; };
    float* feat    = (float*)alloc(16384*4);
    float* feat_tf = (float*)alloc(16384*4);
    float* hbuf    = (float*)alloc(16384*4);
    float* scores  = (float*)alloc(2304*4);
    float* boxes   = (float*)alloc(9216*4);
    int*   order1  = (int*)  alloc(2304*4);
    float* sboxes  = (float*)alloc(9216*4);
    float* sareas  = (float*)alloc(2304*4);
    u64*   supm1   = (u64*)  alloc((size_t)((W1+1)*64)*W1*8);   // +64 slack rows
    u64*   remw1   = (u64*)  alloc(W1*8);
    int*   validat = (int*)  alloc(NP*4);
    float* propws  = (float*)alloc(NP*4*4);
    u16*   wbt     = (u16*)  alloc(36864*2);
    float* flat    = (float*)alloc((size_t)NP*3136*4);
    float* h1      = (float*)alloc((size_t)NP*512*4);
    float* h2      = (float*)alloc((size_t)NP*512*4);
    float* gparts  = (float*)alloc((size_t)7*NP*512*4);     // K-split partials
    float* dets    = (float*)alloc(NP*4*4);
    float* dscores = (float*)alloc(NP*4);
    float* s2      = (float*)alloc(NP*4);
    int*   order2  = (int*)  alloc(NP*4);
    float* sdets   = (float*)alloc(NP*4*4);
    float* sareas2 = (float*)alloc(NP*4);
    u64*   supm2   = (u64*)  alloc((size_t)((W2+1)*64)*W2*8);   // +64 slack rows
    u64*   remw2   = (u64*)  alloc(W2*8);

    // ---- stage 1: backbone + rpn ----
    bb_conv<<<64, 256, 0, stream>>>(x, w_bb, b_bb, feat, feat_tf);
    rpn_conv<<<64, 256, 0, stream>>>(feat, w_rpn, b_rpn, hbuf);
    heads_rpn<<<9, 256, 0, stream>>>(hbuf, w_cls, b_cls, w_box, b_box,
        out + O_RPN_LOGITS, out + O_RPN_DELTAS, out + O_ANCHORS, scores, boxes);

    // ---- NMS 1 ----
    sort_rank<<<9, 256, 0, stream>>>(scores, order1, N_ANCH);
    gather_sorted<<<9, 256, 0, stream>>>((const float4*)boxes, order1,
                                         (float4*)sboxes, sareas, N_ANCH);
    iou_mask<<<(W1*64*W1+255)/256, 256, 0, stream>>>((const float4*)sboxes, sareas,
                                                     N_ANCH, W1*64, W1, 0.5f, supm1);
    nms_scan_wg<<<1, 256, 0, stream>>>(supm1, W1, W1, remw1);
    select_props<<<1, 256, 0, stream>>>(remw1, (const float4*)sboxes,
                                        out + O_PROPOSALS, (float4*)propws, validat);

    // ---- weight prep (independent of NMS; early) ----
    prep_wbt<<<144, 256, 0, stream>>>(w_m1, wbt);

    // ---- RoI head: fused crop+pool+mask first (produces flat) ----
    mask_head_fused<<<NP, 256, 0, stream>>>(feat_tf, (const float4*)propws, wbt,
        b_m1, w_m2, b_m2, out + O_RCNN_MASKS, flat);
    // fc1: K=3136 split 7 x 448 -> 1792 blocks (7/CU)
    gemm_f32_part<<<dim3(32, 8, 7), 256, 0, stream>>>(flat, w_fc1, gparts,
                                                      NP, 512, 3136, 448);
    combine_parts<<<(NP*512/4+255)/256, 256, 0, stream>>>(gparts, b_fc1, h1,
                                                          NP*512, 512, 7, 1);
    // fc2: K=512 split 2 x 256 -> 512 blocks (2/CU)
    gemm_f32_part<<<dim3(32, 8, 2), 256, 0, stream>>>(h1, w_fc2, gparts,
                                                      NP, 512, 512, 256);
    combine_parts<<<(NP*512/4+255)/256, 256, 0, stream>>>(gparts, b_fc2, h2,
                                                          NP*512, 512, 2, 1);
    rcnn_heads_lds<<<250, 256, 0, stream>>>(h2, w_rcls, b_rcls, w_rbox, b_rbox,
        (const float4*)propws, validat, out + O_RCNN_LOGITS, out + O_RCNN_DELTAS,
        (float4*)dets, dscores, s2);

    // ---- NMS 2 + finalize ----
    sort_rank<<<8, 256, 0, stream>>>(s2, order2, NP);
    gather_sorted<<<8, 256, 0, stream>>>((const float4*)dets, order2,
                                         (float4*)sdets, sareas2, NP);
    iou_mask<<<(W2*64*W2+255)/256, 256, 0, stream>>>((const float4*)sdets, sareas2,
                                                     NP, W2*64, W2, 0.3f, supm2);
    nms_scan_wg<<<1, 256, 0, stream>>>(supm2, W2, W2, remw2);
    finalize<<<NP, 256, 0, stream>>>(remw2, order2, validat, (const float4*)dets,
        dscores, out + O_RCNN_MASKS, out + O_FINAL_DETS, out + O_FINAL_SCORES,
        out + O_FINAL_MASKS, out + O_KEEP2);
}

// Round 17
// 642.802 us; speedup vs baseline: 1.0301x; 1.0301x over previous
//
#include <hip/hip_runtime.h>
#include <math.h>

typedef unsigned long long u64;
typedef unsigned short u16;
typedef __attribute__((ext_vector_type(8))) short bf16x8;
typedef __attribute__((ext_vector_type(4))) float f32x4;

#define N_ANCH 2304
#define NP     2000
#define W1     36   // 2304/64
#define W2     32   // ceil(2000/64)

// ---------- output offsets (floats) ----------
#define O_RPN_LOGITS   0
#define O_RPN_DELTAS   4608
#define O_PROPOSALS    13824
#define O_ANCHORS      21824
#define O_RCNN_LOGITS  31040
#define O_RCNN_DELTAS  35040
#define O_RCNN_MASKS   43040
#define O_FINAL_DETS   435040
#define O_FINAL_MASKS  443040
#define O_FINAL_SCORES 835040
#define O_KEEP2        837040

__device__ __forceinline__ u16 f2bf(float f) {
    unsigned int x = __float_as_uint(f);
    unsigned int r = x + 0x7fffu + ((x >> 16) & 1u);   // RTNE
    return (u16)(r >> 16);
}

// ============================================================
// K1: backbone conv + relu -> feat [64,16,16] and feat_tf [pix][64]
// ============================================================
__global__ __launch_bounds__(256) void bb_conv(const float* __restrict__ x,
    const float* __restrict__ w, const float* __restrict__ b,
    float* __restrict__ feat, float* __restrict__ feat_tf)
{
    __shared__ float ws_[768];
    int c = blockIdx.x;
    for (int e = threadIdx.x; e < 768; e += 256) ws_[e] = w[c*768 + e];
    __syncthreads();
    int fy = threadIdx.x >> 4, fx = threadIdx.x & 15;
    float acc = b[c];
    for (int ic = 0; ic < 3; ++ic)
        for (int ky = 0; ky < 16; ++ky) {
            const float* xr = x + (size_t)(ic*256 + fy*16+ky)*256 + fx*16;
            const float* wr = ws_ + ic*256 + ky*16;
            #pragma unroll
            for (int kx = 0; kx < 16; ++kx) acc += xr[kx]*wr[kx];
        }
    float v = fmaxf(acc, 0.f);
    feat[c*256 + threadIdx.x] = v;
    feat_tf[threadIdx.x*64 + c] = v;
}

// ============================================================
// K2: RPN 3x3 SAME conv + relu -> h [64,16,16]
// ============================================================
__global__ __launch_bounds__(256) void rpn_conv(const float* __restrict__ feat,
    const float* __restrict__ w, const float* __restrict__ b, float* __restrict__ h)
{
    __shared__ float f[16384];
    __shared__ float ws_[576];
    int c = blockIdx.x;
    for (int e = threadIdx.x; e < 16384; e += 256) f[e] = feat[e];
    for (int e = threadIdx.x; e < 576; e += 256) ws_[e] = w[c*576 + e];
    __syncthreads();
    int fy = threadIdx.x >> 4, fx = threadIdx.x & 15;
    float acc = b[c];
    for (int ic = 0; ic < 64; ++ic) {
        const float* fc = f + ic*256;
        const float* wc = ws_ + ic*9;
        #pragma unroll
        for (int dy = 0; dy < 3; ++dy) {
            int y = fy + dy - 1;
            if (y < 0 || y > 15) continue;
            #pragma unroll
            for (int dx = 0; dx < 3; ++dx) {
                int xx = fx + dx - 1;
                if (xx < 0 || xx > 15) continue;
                acc += fc[y*16+xx]*wc[dy*3+dx];
            }
        }
    }
    h[c*256 + threadIdx.x] = fmaxf(acc, 0.f);
}

// ============================================================
// K3: RPN heads (1x1 convs) + softmax + anchors + decode + clip
// ============================================================
__global__ __launch_bounds__(256) void heads_rpn(const float* __restrict__ hbuf,
    const float* __restrict__ w_cls, const float* __restrict__ b_cls,
    const float* __restrict__ w_box, const float* __restrict__ b_box,
    float* __restrict__ out_logits, float* __restrict__ out_deltas,
    float* __restrict__ out_anchors,
    float* __restrict__ scores, float* __restrict__ boxes)
{
    int idx = blockIdx.x*256 + threadIdx.x;
    if (idx >= N_ANCH) return;
    int fy = idx / 144, r = idx % 144, fx = r / 9, a = r % 9;
    int pix = fy*16 + fx;
    float l0 = b_cls[a*2+0], l1 = b_cls[a*2+1];
    float d0 = b_box[a*4+0], d1 = b_box[a*4+1], d2 = b_box[a*4+2], d3 = b_box[a*4+3];
    const float* wc0 = w_cls + (a*2+0)*64;
    const float* wc1 = w_cls + (a*2+1)*64;
    const float* wb0 = w_box + (a*4+0)*64;
    const float* wb1 = w_box + (a*4+1)*64;
    const float* wb2 = w_box + (a*4+2)*64;
    const float* wb3 = w_box + (a*4+3)*64;
    for (int c = 0; c < 64; ++c) {
        float hv = hbuf[c*256 + pix];
        l0 += hv*wc0[c]; l1 += hv*wc1[c];
        d0 += hv*wb0[c]; d1 += hv*wb1[c]; d2 += hv*wb2[c]; d3 += hv*wb3[c];
    }
    out_logits[idx*2+0] = l0; out_logits[idx*2+1] = l1;
    out_deltas[idx*4+0] = d0; out_deltas[idx*4+1] = d1;
    out_deltas[idx*4+2] = d2; out_deltas[idx*4+3] = d3;
    float mx = fmaxf(l0,l1);
    float e0 = expf(l0-mx), e1 = expf(l1-mx);
    scores[idx] = e1/(e0+e1);
    float SC = (a/3 == 0) ? 32.f : ((a/3 == 1) ? 64.f : 128.f);
    float RT = (a%3 == 0) ? 0.5f : ((a%3 == 1) ? 1.f : 2.f);
    float wsz = SC*sqrtf(RT), hsz = SC/sqrtf(RT);
    float cx = (fx+0.5f)*16.f, cy = (fy+0.5f)*16.f;
    float ax1 = cx - wsz*0.5f, ay1 = cy - hsz*0.5f;
    float ax2 = cx + wsz*0.5f, ay2 = cy + hsz*0.5f;
    out_anchors[idx*4+0]=ax1; out_anchors[idx*4+1]=ay1;
    out_anchors[idx*4+2]=ax2; out_anchors[idx*4+3]=ay2;
    float aw = ax2-ax1, ah = ay2-ay1;
    float acx = ax1 + 0.5f*aw, acy = ay1 + 0.5f*ah;
    float ncx = acx + d0*aw, ncy = acy + d1*ah;
    float nw = aw*expf(d2), nh = ah*expf(d3);
    float x1 = ncx - 0.5f*nw, y1 = ncy - 0.5f*nh;
    float x2 = ncx + 0.5f*nw, y2 = ncy + 0.5f*nh;
    const float lim = 255.f;
    x1 = fminf(fmaxf(x1,0.f),lim); y1 = fminf(fmaxf(y1,0.f),lim);
    x2 = fminf(fmaxf(x2,0.f),lim); y2 = fminf(fmaxf(y2,0.f),lim);
    boxes[idx*4+0]=x1; boxes[idx*4+1]=y1; boxes[idx*4+2]=x2; boxes[idx*4+3]=y2;
}

// ============================================================
// stable descending argsort by rank counting (matches jnp.argsort(-s))
// ============================================================
__global__ __launch_bounds__(256) void sort_rank(const float* __restrict__ score,
                                                 int* __restrict__ order, int n)
{
    __shared__ float sc[2304];
    for (int i = threadIdx.x; i < n; i += 256) sc[i] = score[i];
    __syncthreads();
    int i = blockIdx.x*256 + threadIdx.x;
    if (i >= n) return;
    float si = sc[i];
    int r = 0;
    for (int j = 0; j < n; ++j) {
        float sj = sc[j];
        r += (sj > si) || (sj == si && j < i);
    }
    order[r] = i;
}

__global__ __launch_bounds__(256) void gather_sorted(const float4* __restrict__ boxes,
    const int* __restrict__ order, float4* __restrict__ sb, float* __restrict__ sa, int n)
{
    int i = blockIdx.x*256 + threadIdx.x;
    if (i >= n) return;
    float4 b = boxes[order[i]];
    sb[i] = b;
    sa[i] = fmaxf(b.z-b.x, 0.f)*fmaxf(b.w-b.y, 0.f);
}

// ============================================================
// IoU suppression bitmask (bits only for j > i); rows [n, ntotal) zeroed
// ============================================================
__global__ __launch_bounds__(256) void iou_mask(const float4* __restrict__ sb,
    const float* __restrict__ sa, int n, int ntotal, int words, float thr,
    u64* __restrict__ mask)
{
    int gid = blockIdx.x*256 + threadIdx.x;
    if (gid >= ntotal*words) return;
    int i = gid / words, w = gid % words;
    if (i >= n) { mask[(size_t)i*words + w] = 0; return; }
    float4 bi = sb[i]; float ai = sa[i];
    u64 m = 0;
    int j0 = w*64;
    for (int bb = 0; bb < 64; ++bb) {
        int j = j0 + bb;
        if (j > i && j < n) {
            float4 bj = sb[j];
            float xx1 = fmaxf(bi.x, bj.x), yy1 = fmaxf(bi.y, bj.y);
            float xx2 = fminf(bi.z, bj.z), yy2 = fminf(bi.w, bj.w);
            float inter = fmaxf(xx2-xx1, 0.f)*fmaxf(yy2-yy1, 0.f);
            float iou = inter / (ai + sa[j] - inter + 1e-8f);
            if (iou > thr) m |= 1ULL << bb;
        }
    }
    mask[(size_t)i*words + w] = m;
}

// ============================================================
// workgroup-parallel blocked greedy NMS scan (256 threads).
// ALL global loads unconditional (clamped; dupes idempotent under AND).
// mask must have (nblk+1)*64 rows allocated (last 64 = slack).
// ============================================================
__global__ __launch_bounds__(256, 1) void nms_scan_wg(const u64* __restrict__ mask,
    int nblk, int words, u64* __restrict__ remout)
{
    __shared__ u64 rem_lds[64];
    __shared__ u64 diagS[64];
    __shared__ u64 pslot[8*64];
    int t = threadIdx.x;
    int ngrp = 256 / words;              // 36->7, 32->8
    int g = t / words, c = t % words;
    bool pactive = (g < ngrp);
    int gg = min(g, ngrp - 1);
    if (t < 64) {
        rem_lds[t] = ~0ULL;
        diagS[t] = mask[(size_t)t*words + 0];
    }
    __syncthreads();
    for (int b = 0; b < nblk; ++b) {
        const u64* blockbase = mask + (size_t)(64*b)*words;
        u64 vals[10];
        int rows[10];
        #pragma unroll
        for (int k = 0; k < 10; ++k) {
            int r = min(gg + k*ngrp, 63);
            rows[k] = r;
            vals[k] = blockbase[(size_t)r*words + c];
        }
        u64 dnext = mask[(size_t)(64*(b+1) + (t & 63))*words + min(b+1, words-1)];
        // sparse serial resolve (readlane on chain)
        u64 mydia = diagS[t & 63];
        u64 nz = __ballot(mydia != 0ULL);
        u64 cur = rem_lds[b];
        u64 pend = cur & nz;
        unsigned mlo = (unsigned)mydia;
        unsigned mhi = (unsigned)(mydia >> 32);
        while (pend) {
            int i = __ffsll((unsigned long long)pend) - 1;
            unsigned lo = __builtin_amdgcn_readlane((int)mlo, i);
            unsigned hi = __builtin_amdgcn_readlane((int)mhi, i);
            u64 dia = ((u64)hi << 32) | lo;
            cur  &= ~dia;
            pend &= ~dia;
            pend &= pend - 1;
        }
        u64 partial = ~0ULL;
        #pragma unroll
        for (int k = 0; k < 10; ++k) {
            bool al = (cur >> rows[k]) & 1ULL;
            partial &= al ? ~vals[k] : ~0ULL;
        }
        if (pactive) pslot[g*64 + c] = partial;
        __syncthreads();
        if (t < 64) diagS[t] = dnext;
        if (t < words) {
            u64 red = rem_lds[t];
            for (int g2 = 0; g2 < ngrp; ++g2) red &= pslot[g2*64 + t];
            rem_lds[t] = red;
        }
        __syncthreads();
    }
    if (t < words) remout[t] = rem_lds[t];
}

// ============================================================
// kept-first stable selection -> proposals / valid
// ============================================================
__global__ __launch_bounds__(256) void select_props(const u64* __restrict__ remw,
    const float4* __restrict__ sboxes, float* __restrict__ prop_out,
    float4* __restrict__ propws, int* __restrict__ validat)
{
    __shared__ int cnt[256];
    __shared__ int pref[257];
    int t = threadIdx.x;
    int base = t*9;
    int c = 0;
    #pragma unroll
    for (int q = 0; q < 9; ++q) { int i = base+q; c += (int)((remw[i>>6]>>(i&63))&1ULL); }
    cnt[t] = c; __syncthreads();
    if (t == 0) { pref[0]=0; for (int u=0;u<256;u++) pref[u+1]=pref[u]+cnt[u]; }
    __syncthreads();
    int K = pref[256];
    int kb = pref[t];
    int nb = K + (base - pref[t]);
    for (int q = 0; q < 9; ++q) {
        int i = base + q;
        int k = (int)((remw[i>>6]>>(i&63))&1ULL);
        int pos = k ? kb : nb;
        if (k) kb++; else nb++;
        if (pos < NP) {
            validat[pos] = k;
            float4 p = k ? sboxes[i] : make_float4(0.f,0.f,0.f,0.f);
            propws[pos] = p;
            prop_out[pos*4+0]=p.x; prop_out[pos*4+1]=p.y;
            prop_out[pos*4+2]=p.z; prop_out[pos*4+3]=p.w;
        }
    }
}

// ============================================================
// weight prep for MFMA mask conv: wbt[tap][oc][ic] (bf16)
// ============================================================
__global__ __launch_bounds__(256) void prep_wbt(const float* __restrict__ w, u16* __restrict__ wbt)
{
    int e = blockIdx.x*256 + threadIdx.x;
    if (e >= 36864) return;
    int oc = e / 576, rem = e % 576, ic = rem / 9, tap = rem % 9;
    wbt[tap*4096 + oc*64 + ic] = f2bf(w[e]);
}

// ============================================================
// K10: FUSED crop + 2x2 maxpool (-> flat, bit-exact f32) + MFMA mask head.
// (R15 variant — best measured: 110 us, 28% occupancy.)
// ============================================================
__global__ __launch_bounds__(256) void mask_head_fused(const float* __restrict__ feat_tf,
    const float4* __restrict__ propws, const u16* __restrict__ wbt,
    const float* __restrict__ b_m1, const float* __restrict__ w_m2,
    const float* __restrict__ b_m2, float* __restrict__ masks_out,
    float* __restrict__ flat)
{
    __shared__ __align__(16) u16 crop[256*72];
    __shared__ unsigned pooled[3136];
    __shared__ float part[4*208];
    int n = blockIdx.x;
    int t = threadIdx.x;
    float4 p = propws[n];
    float x1n = p.x*(1.f/255.f), y1n = p.y*(1.f/255.f);
    float x2n = p.z*(1.f/255.f), y2n = p.w*(1.f/255.f);
    for (int e = t; e < 3136; e += 256) pooled[e] = 0;
    __syncthreads();
    int wave = t >> 6, lane = t & 63;
    for (int it = 0; it < 64; ++it) {
        int g = it*4 + wave;                 // wave-uniform
        int py = (g >> 4) - 1, px = (g & 15) - 1;
        u16 ov = 0;
        if ((unsigned)py < 14u && (unsigned)px < 14u) {   // uniform branch
            float fyv = (y1n + (y2n-y1n)*(py*(1.f/13.f)))*15.f;
            float fxv = (x1n + (x2n-x1n)*(px*(1.f/13.f)))*15.f;
            int y0 = min(max((int)floorf(fyv),0),15), y1i = min(y0+1,15);
            int x0 = min(max((int)floorf(fxv),0),15), x1i = min(x0+1,15);
            float wy = fyv - (float)y0, wx = fxv - (float)x0;
            float v00 = feat_tf[(y0*16+x0)*64 + lane];
            float v01 = feat_tf[(y0*16+x1i)*64 + lane];
            float v10 = feat_tf[(y1i*16+x0)*64 + lane];
            float v11 = feat_tf[(y1i*16+x1i)*64 + lane];
            float top = v00*(1.f-wx) + v01*wx;
            float bot = v10*(1.f-wx) + v11*wx;
            float val = top*(1.f-wy) + bot*wy;
            ov = f2bf(val);
            int q = (py >> 1)*7 + (px >> 1);
            atomicMax(&pooled[lane*49 + q], __float_as_uint(val));
        }
        crop[g*72 + lane] = ov;
    }
    __syncthreads();
    // emit flat (bit-exact pooled max)
    {
        size_t rowoff = (size_t)n*3136;
        for (int k = t; k < 3136; k += 256)
            flat[rowoff + k] = __uint_as_float(pooled[k]);
    }

    int quad = lane >> 4, l15 = lane & 15;
    int oc = wave*16 + l15;
    float biasv = b_m1[oc];
    f32x4 acc[13];
    #pragma unroll
    for (int pt = 0; pt < 13; ++pt) acc[pt] = (f32x4){biasv, biasv, biasv, biasv};

    int prow[13];
    #pragma unroll
    for (int pt = 0; pt < 13; ++pt) {
        int pix = pt*16 + l15;
        int py = pix / 14, px = pix - py*14;
        prow[pt] = (pix < 196) ? ((py+1)*16 + px + 1) : 17;   // pads alias row 17
    }

    const u16* wb_oc = wbt + oc*64;
    for (int tap = 0; tap < 9; ++tap) {
        int doff = (tap/3 - 1)*16 + (tap%3 - 1);
        bf16x8 b0 = *(const bf16x8*)(wb_oc + tap*4096 +      quad*8);
        bf16x8 b1 = *(const bf16x8*)(wb_oc + tap*4096 + 32 + quad*8);
        #pragma unroll
        for (int pt = 0; pt < 13; ++pt) {
            int base = (prow[pt] + doff)*72 + quad*8;
            bf16x8 a0 = *(const bf16x8*)(crop + base);
            bf16x8 a1 = *(const bf16x8*)(crop + base + 32);
            acc[pt] = __builtin_amdgcn_mfma_f32_16x16x32_bf16(a0, b0, acc[pt], 0, 0, 0);
            acc[pt] = __builtin_amdgcn_mfma_f32_16x16x32_bf16(a1, b1, acc[pt], 0, 0, 0);
        }
    }

    float wm2v = w_m2[oc];
    #pragma unroll
    for (int pt = 0; pt < 13; ++pt) {
        #pragma unroll
        for (int r = 0; r < 4; ++r) {
            float s = fmaxf(acc[pt][r], 0.f) * wm2v;
            s += __shfl_xor(s, 1);
            s += __shfl_xor(s, 2);
            s += __shfl_xor(s, 4);
            s += __shfl_xor(s, 8);
            if (l15 == 0) part[wave*208 + pt*16 + quad*4 + r] = s;
        }
    }
    __syncthreads();
    for (int tt = t; tt < 196; tt += 256)
        masks_out[(size_t)n*196 + tt] = part[tt] + part[208+tt] + part[416+tt] + part[624+tt] + b_m2[0];
}

// ============================================================
// f32 GEMM partial over K-split (exact fmaf chain per k-range).
// ============================================================
__global__ __launch_bounds__(256) void gemm_f32_part(const float* __restrict__ A,
    const float* __restrict__ B, float* __restrict__ Cpart,
    int M, int N, int K, int Kblk)
{
    __shared__ float As[32][68];
    __shared__ float Bs[32][68];
    int row0 = blockIdx.x*64, col0 = blockIdx.y*64;
    int s = blockIdx.z;
    int kbase = s*Kblk;
    int t = threadIdx.x;
    int tx = t & 15, ty = t >> 4;
    int ar = t >> 2;
    int ak = (t & 3) * 8;
    int am = min(row0 + ar, M-1);
    const float* Arow = A + (size_t)am*K + kbase;
    int bk = t >> 3;
    int bc = (t & 7) * 8;
    const float* Bbase = B + (size_t)(kbase + bk)*N + col0 + bc;

    float4 pa0 = *(const float4*)(Arow + ak);
    float4 pa1 = *(const float4*)(Arow + ak + 4);
    float4 pb0 = *(const float4*)(Bbase);
    float4 pb1 = *(const float4*)(Bbase + 4);

    float acc[4][4] = {};
    for (int k0 = 0; k0 < Kblk; k0 += 32) {
        As[ak+0][ar]=pa0.x; As[ak+1][ar]=pa0.y; As[ak+2][ar]=pa0.z; As[ak+3][ar]=pa0.w;
        As[ak+4][ar]=pa1.x; As[ak+5][ar]=pa1.y; As[ak+6][ar]=pa1.z; As[ak+7][ar]=pa1.w;
        *(float4*)&Bs[bk][bc]   = pb0;
        *(float4*)&Bs[bk][bc+4] = pb1;
        __syncthreads();
        int kn = k0 + 32;
        if (kn < Kblk) {
            pa0 = *(const float4*)(Arow + kn + ak);
            pa1 = *(const float4*)(Arow + kn + ak + 4);
            pb0 = *(const float4*)(Bbase + (size_t)kn*N);
            pb1 = *(const float4*)(Bbase + (size_t)kn*N + 4);
        }
        #pragma unroll
        for (int k = 0; k < 32; ++k) {
            float4 av = *(float4*)&As[k][ty*4];
            float4 bv = *(float4*)&Bs[k][tx*4];
            float a_[4] = {av.x, av.y, av.z, av.w};
            float b_[4] = {bv.x, bv.y, bv.z, bv.w};
            #pragma unroll
            for (int i = 0; i < 4; ++i)
                #pragma unroll
                for (int j = 0; j < 4; ++j)
                    acc[i][j] = fmaf(a_[i], b_[j], acc[i][j]);
        }
        __syncthreads();
    }
    float* Cp = Cpart + (size_t)s*M*N;
    #pragma unroll
    for (int i = 0; i < 4; ++i) {
        int gm = row0 + ty*4 + i;
        if (gm >= M) continue;
        #pragma unroll
        for (int j = 0; j < 4; ++j) {
            int gn = col0 + tx*4 + j;
            Cp[(size_t)gm*N + gn] = acc[i][j];
        }
    }
}

// ============================================================
// combine K-split partials in ascending-s order + bias + optional relu.
// ============================================================
__global__ __launch_bounds__(256) void combine_parts(const float* __restrict__ parts,
    const float* __restrict__ bias, float* __restrict__ C,
    int MN, int N, int S, int relu)
{
    int i4 = blockIdx.x*256 + threadIdx.x;
    if (i4*4 >= MN) return;
    size_t idx = (size_t)i4*4;
    float4 acc = *(const float4*)(parts + idx);
    for (int s = 1; s < S; ++s) {
        float4 v = *(const float4*)(parts + (size_t)s*MN + idx);
        acc.x += v.x; acc.y += v.y; acc.z += v.z; acc.w += v.w;
    }
    int nb = (int)(idx & (N-1));
    float4 bv = *(const float4*)(bias + nb);
    acc.x += bv.x; acc.y += bv.y; acc.z += bv.z; acc.w += bv.w;
    if (relu) {
        acc.x = fmaxf(acc.x, 0.f); acc.y = fmaxf(acc.y, 0.f);
        acc.z = fmaxf(acc.z, 0.f); acc.w = fmaxf(acc.w, 0.f);
    }
    *(float4*)(C + idx) = acc;
}

// ============================================================
// K9: rcnn heads — coalesced LDS staging, then 8 serial threads replay
// the sequential fmaf chain bit-exactly.
// ============================================================
__global__ __launch_bounds__(256) void rcnn_heads_lds(const float* __restrict__ h2,
    const float* __restrict__ w_rcls, const float* __restrict__ b_rcls,
    const float* __restrict__ w_rbox, const float* __restrict__ b_rbox,
    const float4* __restrict__ propws, const int* __restrict__ validat,
    float* __restrict__ out_logits, float* __restrict__ out_deltas,
    float4* __restrict__ dets, float* __restrict__ dscores, float* __restrict__ s2)
{
    __shared__ float hs[8*520];
    int b0 = blockIdx.x*8;
    for (int e = threadIdx.x; e < 8*512; e += 256) {
        int pr = e >> 9, k = e & 511;
        hs[pr*520 + k] = h2[(size_t)(b0+pr)*512 + k];
    }
    __syncthreads();
    int t = threadIdx.x;
    if (t >= 8) return;
    int n = b0 + t;
    const float* hv = hs + t*520;
    float l0 = b_rcls[0], l1 = b_rcls[1];
    float d0 = b_rbox[0], d1 = b_rbox[1], d2 = b_rbox[2], d3 = b_rbox[3];
    for (int k = 0; k < 512; ++k) {
        float v = hv[k];
        l0 = fmaf(v, w_rcls[k*2+0], l0); l1 = fmaf(v, w_rcls[k*2+1], l1);
        d0 = fmaf(v, w_rbox[k*4+0], d0); d1 = fmaf(v, w_rbox[k*4+1], d1);
        d2 = fmaf(v, w_rbox[k*4+2], d2); d3 = fmaf(v, w_rbox[k*4+3], d3);
    }
    out_logits[n*2+0]=l0; out_logits[n*2+1]=l1;
    out_deltas[n*4+0]=d0; out_deltas[n*4+1]=d1;
    out_deltas[n*4+2]=d2; out_deltas[n*4+3]=d3;
    float mx = fmaxf(l0,l1);
    float e0 = expf(l0-mx), e1 = expf(l1-mx);
    float sc = e1/(e0+e1);
    float4 p = propws[n];
    float w = p.z-p.x, h = p.w-p.y;
    float cx = p.x + 0.5f*w, cy = p.y + 0.5f*h;
    float ncx = cx + d0*w, ncy = cy + d1*h;
    float nw = w*expf(d2), nh = h*expf(d3);
    float x1 = ncx-0.5f*nw, y1 = ncy-0.5f*nh, x2 = ncx+0.5f*nw, y2 = ncy+0.5f*nh;
    const float lim = 255.f;
    x1 = fminf(fmaxf(x1,0.f),lim); y1 = fminf(fmaxf(y1,0.f),lim);
    x2 = fminf(fmaxf(x2,0.f),lim); y2 = fminf(fmaxf(y2,0.f),lim);
    dets[n] = make_float4(x1,y1,x2,y2);
    dscores[n] = sc;
    s2[n] = validat[n] ? sc : -1.0f;
}

// ============================================================
// final outputs
// ============================================================
__global__ void finalize(const u64* __restrict__ remw2,
    const int* __restrict__ order2, const int* __restrict__ validat,
    const float4* __restrict__ dets, const float* __restrict__ dscores,
    const float* __restrict__ masks_in, float* __restrict__ fdets,
    float* __restrict__ fscores, float* __restrict__ fmasks, float* __restrict__ keep2out)
{
    int j = blockIdx.x;
    int t = threadIdx.x;
    int o = order2[j];
    int kb = (int)((remw2[j>>6] >> (j&63)) & 1ULL);
    int k2 = kb & validat[o];
    if (t == 0) {
        float4 d = dets[o];
        if (!k2) d = make_float4(0.f,0.f,0.f,0.f);
        fdets[j*4+0]=d.x; fdets[j*4+1]=d.y; fdets[j*4+2]=d.z; fdets[j*4+3]=d.w;
        fscores[j] = k2 ? dscores[o] : 0.f;
        keep2out[j] = (float)k2;
    }
    if (t < 196) {
        float mv = masks_in[(size_t)o*196 + t];
        float sg = 1.f/(1.f + expf(-mv));
        fmasks[(size_t)j*196 + t] = k2 ? sg : 0.f;
    }
}

// ============================================================
extern "C" void kernel_launch(void* const* d_in, const int* in_sizes, int n_in,
                              void* d_out, int out_size, void* d_ws, size_t ws_size,
                              hipStream_t stream)
{
    const float* x      = (const float*)d_in[0];
    const float* w_bb   = (const float*)d_in[1];
    const float* b_bb   = (const float*)d_in[2];
    const float* w_rpn  = (const float*)d_in[3];
    const float* b_rpn  = (const float*)d_in[4];
    const float* w_cls  = (const float*)d_in[5];
    const float* b_cls  = (const float*)d_in[6];
    const float* w_box  = (const float*)d_in[7];
    const float* b_box  = (const float*)d_in[8];
    const float* w_fc1  = (const float*)d_in[9];
    const float* b_fc1  = (const float*)d_in[10];
    const float* w_fc2  = (const float*)d_in[11];
    const float* b_fc2  = (const float*)d_in[12];
    const float* w_rcls = (const float*)d_in[13];
    const float* b_rcls = (const float*)d_in[14];
    const float* w_rbox = (const float*)d_in[15];
    const float* b_rbox = (const float*)d_in[16];
    const float* w_m1   = (const float*)d_in[17];
    const float* b_m1   = (const float*)d_in[18];
    const float* w_m2   = (const float*)d_in[19];
    const float* b_m2   = (const float*)d_in[20];

    float* out = (float*)d_out;

    // ---- workspace carve-up (256B-aligned chunks) ----
    char* basep = (char*)d_ws;
    auto alloc = [&](size_t bytes) { char* q = basep; basep += (bytes + 255) & ~(size_t)255; return q; };
    float* feat    = (float*)alloc(16384*4);
    float* feat_tf = (float*)alloc(16384*4);
    float* hbuf    = (float*)alloc(16384*4);
    float* scores  = (float*)alloc(2304*4);
    float* boxes   = (float*)alloc(9216*4);
    int*   order1  = (int*)  alloc(2304*4);
    float* sboxes  = (float*)alloc(9216*4);
    float* sareas  = (float*)alloc(2304*4);
    u64*   supm1   = (u64*)  alloc((size_t)((W1+1)*64)*W1*8);   // +64 slack rows
    u64*   remw1   = (u64*)  alloc(W1*8);
    int*   validat = (int*)  alloc(NP*4);
    float* propws  = (float*)alloc(NP*4*4);
    u16*   wbt     = (u16*)  alloc(36864*2);
    float* flat    = (float*)alloc((size_t)NP*3136*4);
    float* h1      = (float*)alloc((size_t)NP*512*4);
    float* h2      = (float*)alloc((size_t)NP*512*4);
    float* gparts  = (float*)alloc((size_t)7*NP*512*4);     // K-split partials
    float* dets    = (float*)alloc(NP*4*4);
    float* dscores = (float*)alloc(NP*4);
    float* s2      = (float*)alloc(NP*4);
    int*   order2  = (int*)  alloc(NP*4);
    float* sdets   = (float*)alloc(NP*4*4);
    float* sareas2 = (float*)alloc(NP*4);
    u64*   supm2   = (u64*)  alloc((size_t)((W2+1)*64)*W2*8);   // +64 slack rows
    u64*   remw2   = (u64*)  alloc(W2*8);

    // ---- stage 1: backbone + rpn ----
    bb_conv<<<64, 256, 0, stream>>>(x, w_bb, b_bb, feat, feat_tf);
    rpn_conv<<<64, 256, 0, stream>>>(feat, w_rpn, b_rpn, hbuf);
    heads_rpn<<<9, 256, 0, stream>>>(hbuf, w_cls, b_cls, w_box, b_box,
        out + O_RPN_LOGITS, out + O_RPN_DELTAS, out + O_ANCHORS, scores, boxes);

    // ---- NMS 1 ----
    sort_rank<<<9, 256, 0, stream>>>(scores, order1, N_ANCH);
    gather_sorted<<<9, 256, 0, stream>>>((const float4*)boxes, order1,
                                         (float4*)sboxes, sareas, N_ANCH);
    iou_mask<<<(W1*64*W1+255)/256, 256, 0, stream>>>((const float4*)sboxes, sareas,
                                                     N_ANCH, W1*64, W1, 0.5f, supm1);
    nms_scan_wg<<<1, 256, 0, stream>>>(supm1, W1, W1, remw1);
    select_props<<<1, 256, 0, stream>>>(remw1, (const float4*)sboxes,
                                        out + O_PROPOSALS, (float4*)propws, validat);

    // ---- weight prep (independent of NMS; early) ----
    prep_wbt<<<144, 256, 0, stream>>>(w_m1, wbt);

    // ---- RoI head: fused crop+pool+mask first (produces flat) ----
    mask_head_fused<<<NP, 256, 0, stream>>>(feat_tf, (const float4*)propws, wbt,
        b_m1, w_m2, b_m2, out + O_RCNN_MASKS, flat);
    // fc1: K=3136 split 7 x 448 -> 1792 blocks (7/CU)
    gemm_f32_part<<<dim3(32, 8, 7), 256, 0, stream>>>(flat, w_fc1, gparts,
                                                      NP, 512, 3136, 448);
    combine_parts<<<(NP*512/4+255)/256, 256, 0, stream>>>(gparts, b_fc1, h1,
                                                          NP*512, 512, 7, 1);
    // fc2: K=512 split 2 x 256 -> 512 blocks (2/CU)
    gemm_f32_part<<<dim3(32, 8, 2), 256, 0, stream>>>(h1, w_fc2, gparts,
                                                      NP, 512, 512, 256);
    combine_parts<<<(NP*512/4+255)/256, 256, 0, stream>>>(gparts, b_fc2, h2,
                                                          NP*512, 512, 2, 1);
    rcnn_heads_lds<<<250, 256, 0, stream>>>(h2, w_rcls, b_rcls, w_rbox, b_rbox,
        (const float4*)propws, validat, out + O_RCNN_LOGITS, out + O_RCNN_DELTAS,
        (float4*)dets, dscores, s2);

    // ---- NMS 2 + finalize ----
    sort_rank<<<8, 256, 0, stream>>>(s2, order2, NP);
    gather_sorted<<<8, 256, 0, stream>>>((const float4*)dets, order2,
                                         (float4*)sdets, sareas2, NP);
    iou_mask<<<(W2*64*W2+255)/256, 256, 0, stream>>>((const float4*)sdets, sareas2,
                                                     NP, W2*64, W2, 0.3f, supm2);
    nms_scan_wg<<<1, 256, 0, stream>>>(supm2, W2, W2, remw2);
    finalize<<<NP, 256, 0, stream>>>(remw2, order2, validat, (const float4*)dets,
        dscores, out + O_RCNN_MASKS, out + O_FINAL_DETS, out + O_FINAL_SCORES,
        out + O_FINAL_MASKS, out + O_KEEP2);
}